// Round 1
// baseline (7505.062 us; speedup 1.0000x reference)
//
#include <hip/hip_runtime.h>

// Problem constants: B=2, T=4096, D=2048, N=8 heads, K=1 kv-head, H=256
#define T_SEQ 4096
#define D_MODEL 2048
#define N_HEADS 8
#define HDIM 256

typedef unsigned int uint32;
typedef unsigned short u16;

__device__ __forceinline__ float bf2f(u16 v) {
  return __uint_as_float(((uint32)v) << 16);
}
__device__ __forceinline__ u16 f2bf(float f) {
  uint32 u = __float_as_uint(f);
  u += 0x7fffu + ((u >> 16) & 1u);  // round-to-nearest-even
  return (u16)(u >> 16);
}

// ---------------------------------------------------------------------------
// GEMM 1: QKV projection.  C = x[8192 x 2048] @ W[2048 x 256] per group.
// grid.z = 10 groups: 0..7 -> q_w heads, 8 -> K weights, 9 -> V weights.
// Output stored as bf16 (sets up bf16 attention / future MFMA path).
// 64x64x16 tile, 256 threads, 4x4 microtile.
// ---------------------------------------------------------------------------
__global__ __launch_bounds__(256) void gemm_qkv(
    const float* __restrict__ x, const float* __restrict__ qw,
    const float* __restrict__ kvw, u16* __restrict__ Qb, u16* __restrict__ Kb,
    u16* __restrict__ Vb) {
  __shared__ float As[16][68];  // As[k][m], pad->stride 68 (16B-aligned rows)
  __shared__ float Bs[16][68];  // Bs[k][n]
  const int t = threadIdx.x;
  const int nt = blockIdx.x;  // 0..3   col tile
  const int mt = blockIdx.y;  // 0..127 row tile
  const int g = blockIdx.z;   // 0..9
  const float* Bp = (g < 8) ? (qw + (size_t)g * D_MODEL * HDIM)
                            : (kvw + (size_t)(g - 8) * D_MODEL * HDIM);
  const int row0 = mt * 64, col0 = nt * 64;
  const int tm = t & 15, tn = t >> 4;  // microtile coords (also reused for loads)
  const int lm = t >> 2, lkq = t & 3;  // A-load coords
  float acc[4][4] = {};
  for (int k0 = 0; k0 < D_MODEL; k0 += 16) {
    float4 a4 =
        *(const float4*)(x + (size_t)(row0 + lm) * D_MODEL + k0 + lkq * 4);
    As[lkq * 4 + 0][lm] = a4.x;
    As[lkq * 4 + 1][lm] = a4.y;
    As[lkq * 4 + 2][lm] = a4.z;
    As[lkq * 4 + 3][lm] = a4.w;
    float4 b4 = *(const float4*)(Bp + (size_t)(k0 + tn) * HDIM + col0 + tm * 4);
    *(float4*)&Bs[tn][tm * 4] = b4;
    __syncthreads();
#pragma unroll
    for (int k = 0; k < 16; ++k) {
      float4 a = *(const float4*)&As[k][tm * 4];
      float4 b = *(const float4*)&Bs[k][tn * 4];
      float av[4] = {a.x, a.y, a.z, a.w};
      float bv[4] = {b.x, b.y, b.z, b.w};
#pragma unroll
      for (int i = 0; i < 4; ++i)
#pragma unroll
        for (int j = 0; j < 4; ++j) acc[i][j] = fmaf(av[i], bv[j], acc[i][j]);
    }
    __syncthreads();
  }
#pragma unroll
  for (int i = 0; i < 4; ++i) {
    const int rrow = row0 + tm * 4 + i;
    const int ccol = col0 + tn * 4;
    uint32 lo = (uint32)f2bf(acc[i][0]) | ((uint32)f2bf(acc[i][1]) << 16);
    uint32 hi = (uint32)f2bf(acc[i][2]) | ((uint32)f2bf(acc[i][3]) << 16);
    u16* dst;
    if (g < 8)
      dst = Qb + (size_t)rrow * (N_HEADS * HDIM) + g * HDIM + ccol;
    else if (g == 8)
      dst = Kb + (size_t)rrow * HDIM + ccol;
    else
      dst = Vb + (size_t)rrow * HDIM + ccol;
    *(uint2*)dst = make_uint2(lo, hi);
  }
}

// ---------------------------------------------------------------------------
// RoPE (in-place on bf16 Q and K) + query scaling by H^-0.5.
// One block per (b,t) row.
// ---------------------------------------------------------------------------
__global__ __launch_bounds__(256) void rope_kernel(u16* __restrict__ Qb,
                                                   u16* __restrict__ Kb,
                                                   const int* __restrict__ segpos) {
  const int bt = blockIdx.x;
  const int tid = threadIdx.x;
  const float fpos = (float)segpos[bt];
  const float k_ln = 9.210340371976184f / 128.0f;  // ln(10000)/(H/2)
  for (int p = tid; p < 1024; p += 256) {          // 8 heads x 128 pairs
    const int n = p >> 7, i = p & 127;
    const size_t base = (size_t)bt * (N_HEADS * HDIM) + (size_t)n * HDIM;
    const float th = fpos * expf(-(float)i * k_ln);
    float s, c;
    sincosf(th, &s, &c);
    const float f1 = bf2f(Qb[base + i]);
    const float f2 = bf2f(Qb[base + i + 128]);
    Qb[base + i] = f2bf((f1 * c - f2 * s) * 0.0625f);
    Qb[base + i + 128] = f2bf((f2 * c + f1 * s) * 0.0625f);
  }
  if (tid < 128) {  // single shared KV head
    const int i = tid;
    const size_t base = (size_t)bt * HDIM;
    const float th = fpos * expf(-(float)i * k_ln);
    float s, c;
    sincosf(th, &s, &c);
    const float f1 = bf2f(Kb[base + i]);
    const float f2 = bf2f(Kb[base + i + 128]);
    Kb[base + i] = f2bf(f1 * c - f2 * s);
    Kb[base + i + 128] = f2bf(f2 * c + f1 * s);
  }
}

// ---------------------------------------------------------------------------
// Flash attention, causal, MQA (one KV head shared by 8 Q heads).
// Block = 256 threads handles (b, n, 32 query rows); K/V tiles of 32 staged
// in LDS as bf16 (row stride 264 shorts = conflict-free b128 reads).
// Thread t: row r=t>>3, c=t&7.  Scores: 4 per thread (s = c+8j).
// O accum: row r, h = 4c+32j, j=0..7 (32 f32 regs).
// ---------------------------------------------------------------------------
__global__ __launch_bounds__(256) void attn_kernel(const u16* __restrict__ Qb,
                                                   const u16* __restrict__ Kb,
                                                   const u16* __restrict__ Vb,
                                                   u16* __restrict__ Eb) {
  __shared__ u16 Qs[32][264];
  __shared__ u16 Ks[32][264];
  __shared__ u16 Vs[32][264];
  __shared__ float Ss[32][33];
  const int qt = blockIdx.x, n = blockIdx.y, b = blockIdx.z;
  const int q0 = qt * 32;
  const int t = threadIdx.x;
  const int r = t >> 3, c = t & 7;
  // Load Q tile (32 x 256 bf16), coalesced 16B lanes.
#pragma unroll
  for (int i = 0; i < 4; ++i) {
    const int flat = t + 256 * i;
    const int row = flat >> 5, col8 = (flat & 31) * 8;
    *(uint4*)&Qs[row][col8] = *(const uint4*)(
        Qb + ((size_t)(b * T_SEQ + q0 + row) * N_HEADS + n) * HDIM + col8);
  }
  float4 O[8];
#pragma unroll
  for (int j = 0; j < 8; ++j) O[j] = make_float4(0.f, 0.f, 0.f, 0.f);
  float m_i = -INFINITY, l_i = 0.f;
  const int trow = q0 + r;
  for (int st = 0; st <= qt; ++st) {
    const int s0 = st * 32;
    __syncthreads();  // previous PV must finish before K/V overwrite
#pragma unroll
    for (int i = 0; i < 4; ++i) {
      const int flat = t + 256 * i;
      const int row = flat >> 5, col8 = (flat & 31) * 8;
      const size_t gidx = (size_t)(b * T_SEQ + s0 + row) * HDIM + col8;
      *(uint4*)&Ks[row][col8] = *(const uint4*)(Kb + gidx);
      *(uint4*)&Vs[row][col8] = *(const uint4*)(Vb + gidx);
    }
    __syncthreads();
    // --- scores: S = Q . K^T, 4 per thread ---
    float sc[4] = {0.f, 0.f, 0.f, 0.f};
    for (int h = 0; h < HDIM; h += 8) {
      const uint4 qu = *(const uint4*)&Qs[r][h];
      float qv[8];
      qv[0] = __uint_as_float(qu.x << 16);
      qv[1] = __uint_as_float(qu.x & 0xffff0000u);
      qv[2] = __uint_as_float(qu.y << 16);
      qv[3] = __uint_as_float(qu.y & 0xffff0000u);
      qv[4] = __uint_as_float(qu.z << 16);
      qv[5] = __uint_as_float(qu.z & 0xffff0000u);
      qv[6] = __uint_as_float(qu.w << 16);
      qv[7] = __uint_as_float(qu.w & 0xffff0000u);
#pragma unroll
      for (int j = 0; j < 4; ++j) {
        const uint4 ku = *(const uint4*)&Ks[c + 8 * j][h];
        float kv[8];
        kv[0] = __uint_as_float(ku.x << 16);
        kv[1] = __uint_as_float(ku.x & 0xffff0000u);
        kv[2] = __uint_as_float(ku.y << 16);
        kv[3] = __uint_as_float(ku.y & 0xffff0000u);
        kv[4] = __uint_as_float(ku.z << 16);
        kv[5] = __uint_as_float(ku.z & 0xffff0000u);
        kv[6] = __uint_as_float(ku.w << 16);
        kv[7] = __uint_as_float(ku.w & 0xffff0000u);
#pragma unroll
        for (int u = 0; u < 8; ++u) sc[j] = fmaf(qv[u], kv[u], sc[j]);
      }
    }
    // --- causal mask + online softmax (8-lane butterfly per row) ---
    float tmax = -INFINITY;
#pragma unroll
    for (int j = 0; j < 4; ++j) {
      if (s0 + c + 8 * j > trow) sc[j] = -INFINITY;
      tmax = fmaxf(tmax, sc[j]);
    }
    tmax = fmaxf(tmax, __shfl_xor(tmax, 1));
    tmax = fmaxf(tmax, __shfl_xor(tmax, 2));
    tmax = fmaxf(tmax, __shfl_xor(tmax, 4));
    const float m_new = fmaxf(m_i, tmax);
    const float alpha = __expf(m_i - m_new);  // first tile: exp(-inf)=0
    float rs = 0.f;
#pragma unroll
    for (int j = 0; j < 4; ++j) {
      const float p = __expf(sc[j] - m_new);  // masked -> 0
      Ss[r][c + 8 * j] = p;
      rs += p;
    }
    rs += __shfl_xor(rs, 1);
    rs += __shfl_xor(rs, 2);
    rs += __shfl_xor(rs, 4);
    l_i = l_i * alpha + rs;
    m_i = m_new;
#pragma unroll
    for (int j = 0; j < 8; ++j) {
      O[j].x *= alpha;
      O[j].y *= alpha;
      O[j].z *= alpha;
      O[j].w *= alpha;
    }
    __syncthreads();
    // --- PV accumulate ---
    for (int s = 0; s < 32; ++s) {
      const float p = Ss[r][s];
#pragma unroll
      for (int j = 0; j < 8; ++j) {
        const int h = 4 * c + 32 * j;
        const uint2 vu = *(const uint2*)&Vs[s][h];
        O[j].x = fmaf(p, __uint_as_float(vu.x << 16), O[j].x);
        O[j].y = fmaf(p, __uint_as_float(vu.x & 0xffff0000u), O[j].y);
        O[j].z = fmaf(p, __uint_as_float(vu.y << 16), O[j].z);
        O[j].w = fmaf(p, __uint_as_float(vu.y & 0xffff0000u), O[j].w);
      }
    }
  }
  // epilogue: normalize and store encoded (bf16)
  const float inv_l = 1.0f / l_i;
#pragma unroll
  for (int j = 0; j < 8; ++j) {
    const int h = 4 * c + 32 * j;
    uint32 lo = (uint32)f2bf(O[j].x * inv_l) | ((uint32)f2bf(O[j].y * inv_l) << 16);
    uint32 hi = (uint32)f2bf(O[j].z * inv_l) | ((uint32)f2bf(O[j].w * inv_l) << 16);
    *(uint2*)(Eb + ((size_t)(b * T_SEQ + q0 + r) * N_HEADS + n) * HDIM + h) =
        make_uint2(lo, hi);
  }
}

// ---------------------------------------------------------------------------
// GEMM 3: output projection. out[8192 x 2048] = E(bf16)[8192 x 2048] @
// out_w (viewed as [2048 x 2048] f32, row index = n*256+h).
// ---------------------------------------------------------------------------
__global__ __launch_bounds__(256) void gemm_out(const u16* __restrict__ E,
                                                const float* __restrict__ ow,
                                                float* __restrict__ out) {
  __shared__ float As[16][68];
  __shared__ float Bs[16][68];
  const int t = threadIdx.x;
  const int nt = blockIdx.x;  // 0..31
  const int mt = blockIdx.y;  // 0..127
  const int row0 = mt * 64, col0 = nt * 64;
  const int tm = t & 15, tn = t >> 4;
  const int lm = t >> 2, lkq = t & 3;
  float acc[4][4] = {};
  for (int k0 = 0; k0 < D_MODEL; k0 += 16) {
    const uint2 a2 =
        *(const uint2*)(E + (size_t)(row0 + lm) * D_MODEL + k0 + lkq * 4);
    As[lkq * 4 + 0][lm] = __uint_as_float(a2.x << 16);
    As[lkq * 4 + 1][lm] = __uint_as_float(a2.x & 0xffff0000u);
    As[lkq * 4 + 2][lm] = __uint_as_float(a2.y << 16);
    As[lkq * 4 + 3][lm] = __uint_as_float(a2.y & 0xffff0000u);
    float4 b4 =
        *(const float4*)(ow + (size_t)(k0 + tn) * D_MODEL + col0 + tm * 4);
    *(float4*)&Bs[tn][tm * 4] = b4;
    __syncthreads();
#pragma unroll
    for (int k = 0; k < 16; ++k) {
      float4 a = *(const float4*)&As[k][tm * 4];
      float4 b = *(const float4*)&Bs[k][tn * 4];
      float av[4] = {a.x, a.y, a.z, a.w};
      float bv[4] = {b.x, b.y, b.z, b.w};
#pragma unroll
      for (int i = 0; i < 4; ++i)
#pragma unroll
        for (int j = 0; j < 4; ++j) acc[i][j] = fmaf(av[i], bv[j], acc[i][j]);
    }
    __syncthreads();
  }
#pragma unroll
  for (int i = 0; i < 4; ++i) {
    const int rrow = row0 + tm * 4 + i;
    const int ccol = col0 + tn * 4;
    *(float4*)(out + (size_t)rrow * D_MODEL + ccol) =
        make_float4(acc[i][0], acc[i][1], acc[i][2], acc[i][3]);
  }
}

// ---------------------------------------------------------------------------
extern "C" void kernel_launch(void* const* d_in, const int* in_sizes, int n_in,
                              void* d_out, int out_size, void* d_ws,
                              size_t ws_size, hipStream_t stream) {
  const float* x = (const float*)d_in[0];
  const int* segpos = (const int*)d_in[1];
  // d_in[2] = attn_mask (causal tril) — implemented analytically, not read.
  const float* qw = (const float*)d_in[3];
  const float* kvw = (const float*)d_in[4];
  const float* ow = (const float*)d_in[5];
  float* out = (float*)d_out;

  char* ws = (char*)d_ws;
  u16* Qb = (u16*)ws;                              // 8192*2048 bf16 = 32 MiB
  u16* Kb = (u16*)(ws + (size_t)33554432);         // 8192*256  bf16 = 4 MiB
  u16* Vb = (u16*)(ws + (size_t)33554432 + 4194304);
  u16* Eb = (u16*)(ws + (size_t)33554432 + 8388608);  // 32 MiB

  hipLaunchKernelGGL(gemm_qkv, dim3(4, 128, 10), dim3(256), 0, stream, x, qw,
                     kvw, Qb, Kb, Vb);
  hipLaunchKernelGGL(rope_kernel, dim3(8192), dim3(256), 0, stream, Qb, Kb,
                     segpos);
  hipLaunchKernelGGL(attn_kernel, dim3(128, N_HEADS, 2), dim3(256), 0, stream,
                     Qb, Kb, Vb, Eb);
  hipLaunchKernelGGL(gemm_out, dim3(32, 128), dim3(256), 0, stream, Eb, ow,
                     out);
}

// Round 2
// 2715.366 us; speedup vs baseline: 2.7639x; 2.7639x over previous
//
#include <hip/hip_runtime.h>

// Problem constants: B=2, T=4096, D=2048, N=8 heads, K=1 kv-head, H=256
#define T_SEQ 4096
#define D_MODEL 2048
#define N_HEADS 8
#define HDIM 256

typedef unsigned int uint32;
typedef unsigned short u16;
typedef __attribute__((ext_vector_type(8))) short short8;  // 8 bf16 (4 VGPRs)
typedef __attribute__((ext_vector_type(4))) float f32x4;

__device__ __forceinline__ float bf2f(u16 v) {
  return __uint_as_float(((uint32)v) << 16);
}
__device__ __forceinline__ u16 f2bf(float f) {
  uint32 u = __float_as_uint(f);
  u += 0x7fffu + ((u >> 16) & 1u);  // round-to-nearest-even
  return (u16)(u >> 16);
}

// ---------------------------------------------------------------------------
// GEMM 1: QKV projection.  C = x[8192 x 2048] @ W[2048 x 256] per group.
// grid.z = 10: 0..7 -> q heads, 8 -> K, 9 -> V (V written TRANSPOSED [b][h][s]
// so the attention kernel can read key-contiguous B-fragments).
// ---------------------------------------------------------------------------
__global__ __launch_bounds__(256) void gemm_qkv(
    const float* __restrict__ x, const float* __restrict__ qw,
    const float* __restrict__ kvw, u16* __restrict__ Qb, u16* __restrict__ Kb,
    u16* __restrict__ Vt) {
  __shared__ float As[16][68];
  __shared__ float Bs[16][68];
  __shared__ u16 Ts[64][72];  // V transpose staging (g==9 only)
  const int t = threadIdx.x;
  const int nt = blockIdx.x;  // 0..3
  const int mt = blockIdx.y;  // 0..127
  const int g = blockIdx.z;   // 0..9
  const float* Bp = (g < 8) ? (qw + (size_t)g * D_MODEL * HDIM)
                            : (kvw + (size_t)(g - 8) * D_MODEL * HDIM);
  const int row0 = mt * 64, col0 = nt * 64;
  const int tm = t & 15, tn = t >> 4;
  const int lm = t >> 2, lkq = t & 3;
  float acc[4][4] = {};
  for (int k0 = 0; k0 < D_MODEL; k0 += 16) {
    float4 a4 =
        *(const float4*)(x + (size_t)(row0 + lm) * D_MODEL + k0 + lkq * 4);
    As[lkq * 4 + 0][lm] = a4.x;
    As[lkq * 4 + 1][lm] = a4.y;
    As[lkq * 4 + 2][lm] = a4.z;
    As[lkq * 4 + 3][lm] = a4.w;
    float4 b4 = *(const float4*)(Bp + (size_t)(k0 + tn) * HDIM + col0 + tm * 4);
    *(float4*)&Bs[tn][tm * 4] = b4;
    __syncthreads();
#pragma unroll
    for (int k = 0; k < 16; ++k) {
      float4 a = *(const float4*)&As[k][tm * 4];
      float4 b = *(const float4*)&Bs[k][tn * 4];
      float av[4] = {a.x, a.y, a.z, a.w};
      float bv[4] = {b.x, b.y, b.z, b.w};
#pragma unroll
      for (int i = 0; i < 4; ++i)
#pragma unroll
        for (int j = 0; j < 4; ++j) acc[i][j] = fmaf(av[i], bv[j], acc[i][j]);
    }
    __syncthreads();
  }
  if (g == 9) {
    // transpose the 64x64 tile through LDS; write Vt[b][h][s] coalesced in s
#pragma unroll
    for (int i = 0; i < 4; ++i)
#pragma unroll
      for (int j = 0; j < 4; ++j) Ts[tn * 4 + j][tm * 4 + i] = f2bf(acc[i][j]);
    __syncthreads();
    const int hh = t >> 2, sc4 = t & 3;
    const int bb = row0 >> 12, sbase = row0 & 4095;
    u16* dst =
        Vt + ((size_t)(bb * HDIM + col0 + hh)) * T_SEQ + sbase + sc4 * 16;
    *(uint4*)dst = *(const uint4*)&Ts[hh][sc4 * 16];
    *(uint4*)(dst + 8) = *(const uint4*)&Ts[hh][sc4 * 16 + 8];
    return;
  }
#pragma unroll
  for (int i = 0; i < 4; ++i) {
    const int rrow = row0 + tm * 4 + i;
    const int ccol = col0 + tn * 4;
    uint32 lo = (uint32)f2bf(acc[i][0]) | ((uint32)f2bf(acc[i][1]) << 16);
    uint32 hi = (uint32)f2bf(acc[i][2]) | ((uint32)f2bf(acc[i][3]) << 16);
    u16* dst;
    if (g < 8)
      dst = Qb + (size_t)rrow * (N_HEADS * HDIM) + g * HDIM + ccol;
    else
      dst = Kb + (size_t)rrow * HDIM + ccol;
    *(uint2*)dst = make_uint2(lo, hi);
  }
}

// ---------------------------------------------------------------------------
// RoPE (in-place on bf16 Q and K) + query scaling by H^-0.5.
// ---------------------------------------------------------------------------
__global__ __launch_bounds__(256) void rope_kernel(u16* __restrict__ Qb,
                                                   u16* __restrict__ Kb,
                                                   const int* __restrict__ segpos) {
  const int bt = blockIdx.x;
  const int tid = threadIdx.x;
  const float fpos = (float)segpos[bt];
  const float k_ln = 9.210340371976184f / 128.0f;  // ln(10000)/(H/2)
  for (int p = tid; p < 1024; p += 256) {
    const int n = p >> 7, i = p & 127;
    const size_t base = (size_t)bt * (N_HEADS * HDIM) + (size_t)n * HDIM;
    const float th = fpos * expf(-(float)i * k_ln);
    float s, c;
    sincosf(th, &s, &c);
    const float f1 = bf2f(Qb[base + i]);
    const float f2 = bf2f(Qb[base + i + 128]);
    Qb[base + i] = f2bf((f1 * c - f2 * s) * 0.0625f);
    Qb[base + i + 128] = f2bf((f2 * c + f1 * s) * 0.0625f);
  }
  if (tid < 128) {
    const int i = tid;
    const size_t base = (size_t)bt * HDIM;
    const float th = fpos * expf(-(float)i * k_ln);
    float s, c;
    sincosf(th, &s, &c);
    const float f1 = bf2f(Kb[base + i]);
    const float f2 = bf2f(Kb[base + i + 128]);
    Kb[base + i] = f2bf(f1 * c - f2 * s);
    Kb[base + i + 128] = f2bf(f2 * c + f1 * s);
  }
}

// ---------------------------------------------------------------------------
// MFMA flash attention (causal, MQA).
// Block: 256 thr = 4 waves, 64 Q rows (16/wave), K-tile = 32 keys.
// S = QK^T via mfma_16x16x32_bf16: A = Q frags (regs), B = K tile (LDS,
// [key][h], stride 264 -> 2-way banks = free).  C layout: row(q)=quad*4+reg,
// col(key)=lane&15 -> softmax stats shfl-reduce over lanes 1/2/4/8.
// P -> per-wave LDS patch -> A-fragment (k-contiguous).  V staged from the
// transposed global Vt as [h][key] so PV B-frags are k(key)-contiguous.
// ---------------------------------------------------------------------------
__global__ __launch_bounds__(256) void attn_mfma(const u16* __restrict__ Qb,
                                                 const u16* __restrict__ Kb,
                                                 const u16* __restrict__ Vt,
                                                 u16* __restrict__ Eb) {
  __shared__ u16 Ks[32][264];     // 16.9 KB  [key][h]
  __shared__ u16 Vs[256][40];     // 20.5 KB  [h][key]
  __shared__ u16 Ps[4][16][40];   // 5.1 KB   per-wave P patch
  const int t = threadIdx.x;
  const int w = t >> 6, l = t & 63;
  const int quad = l >> 4, lq = l & 15;
  const int qt = (int)gridDim.x - 1 - (int)blockIdx.x;  // heavy tiles first
  const int n = blockIdx.y, b = blockIdx.z;
  const int q0 = qt * 64;
  const int wrow0 = q0 + w * 16;

  // Q fragments: 8 chunks of K=32 head-dims, held in registers for the block.
  short8 qf[8];
  {
    const u16* qbase =
        Qb + (((size_t)b * T_SEQ + wrow0 + lq) * N_HEADS + n) * HDIM + quad * 8;
#pragma unroll
    for (int c = 0; c < 8; ++c) qf[c] = *(const short8*)(qbase + c * 32);
  }
  f32x4 O[16];
#pragma unroll
  for (int i = 0; i < 16; ++i) O[i] = (f32x4){0.f, 0.f, 0.f, 0.f};
  float m_i[4] = {-1e30f, -1e30f, -1e30f, -1e30f};
  float l_i[4] = {0.f, 0.f, 0.f, 0.f};

  const u16* kgbase = Kb + (size_t)b * T_SEQ * HDIM;
  const u16* vgbase = Vt + (size_t)b * HDIM * T_SEQ;
  const int nst = 2 * qt + 2;
  for (int st = 0; st < nst; ++st) {
    const int s0 = st * 32;
    __syncthreads();  // previous iteration's LDS reads must finish
    // stage K tile: 32 keys x 256 h (16 KB), coalesced 16B lanes
#pragma unroll
    for (int p = 0; p < 4; ++p) {
      const int chunk = p * 256 + t;
      const int row = chunk >> 5, col = chunk & 31;
      *(uint4*)&Ks[row][col * 8] =
          *(const uint4*)(kgbase + (size_t)(s0 + row) * HDIM + col * 8);
    }
    // stage V tile (already transposed in global): 256 h x 32 keys
#pragma unroll
    for (int p = 0; p < 4; ++p) {
      const int chunk = p * 256 + t;
      const int row = chunk >> 2, c4 = chunk & 3;
      *(uint4*)&Vs[row][c4 * 8] =
          *(const uint4*)(vgbase + (size_t)row * T_SEQ + s0 + c4 * 8);
    }
    __syncthreads();
    if (s0 <= wrow0 + 15) {  // wave-uniform: skip fully-masked tiles
      // --- S = Q.K^T ---
      f32x4 sa0 = (f32x4){0.f, 0.f, 0.f, 0.f};
      f32x4 sa1 = (f32x4){0.f, 0.f, 0.f, 0.f};
#pragma unroll
      for (int c = 0; c < 8; ++c) {
        short8 k0 = *(const short8*)&Ks[lq][c * 32 + quad * 8];
        short8 k1 = *(const short8*)&Ks[16 + lq][c * 32 + quad * 8];
        sa0 = __builtin_amdgcn_mfma_f32_16x16x32_bf16(qf[c], k0, sa0, 0, 0, 0);
        sa1 = __builtin_amdgcn_mfma_f32_16x16x32_bf16(qf[c], k1, sa1, 0, 0, 0);
      }
      // --- causal mask (only diagonal tiles need it) ---
      if (s0 + 31 > wrow0) {
#pragma unroll
        for (int r = 0; r < 4; ++r) {
          const int rw = wrow0 + quad * 4 + r;
          if (s0 + lq > rw) sa0[r] = -1e30f;
          if (s0 + 16 + lq > rw) sa1[r] = -1e30f;
        }
      }
      // --- online softmax ---
      float al[4];
#pragma unroll
      for (int r = 0; r < 4; ++r) {
        float mx = fmaxf(sa0[r], sa1[r]);
        mx = fmaxf(mx, __shfl_xor(mx, 1));
        mx = fmaxf(mx, __shfl_xor(mx, 2));
        mx = fmaxf(mx, __shfl_xor(mx, 4));
        mx = fmaxf(mx, __shfl_xor(mx, 8));
        const float mnew = fmaxf(m_i[r], mx);
        const float a = __expf(m_i[r] - mnew);
        const float p0 = __expf(sa0[r] - mnew);
        const float p1 = __expf(sa1[r] - mnew);
        float rs = p0 + p1;
        rs += __shfl_xor(rs, 1);
        rs += __shfl_xor(rs, 2);
        rs += __shfl_xor(rs, 4);
        rs += __shfl_xor(rs, 8);
        l_i[r] = l_i[r] * a + rs;
        m_i[r] = mnew;
        al[r] = a;
        Ps[w][quad * 4 + r][lq] = f2bf(p0);
        Ps[w][quad * 4 + r][16 + lq] = f2bf(p1);
      }
#pragma unroll
      for (int ntl = 0; ntl < 16; ++ntl) {
        O[ntl][0] *= al[0];
        O[ntl][1] *= al[1];
        O[ntl][2] *= al[2];
        O[ntl][3] *= al[3];
      }
      // wave-local LDS round-trip: drain writes before the fragment read
      __asm__ volatile("s_waitcnt lgkmcnt(0)" ::: "memory");
      short8 pf = *(const short8*)&Ps[w][lq][quad * 8];
      // --- O += P.V ---
#pragma unroll
      for (int ntl = 0; ntl < 16; ++ntl) {
        short8 vf = *(const short8*)&Vs[ntl * 16 + lq][quad * 8];
        O[ntl] = __builtin_amdgcn_mfma_f32_16x16x32_bf16(pf, vf, O[ntl], 0, 0, 0);
      }
    }
  }
  // epilogue: normalize, store encoded bf16
  float inv[4];
#pragma unroll
  for (int r = 0; r < 4; ++r) inv[r] = 1.0f / l_i[r];
  u16* ebase =
      Eb + (((size_t)b * T_SEQ + wrow0 + quad * 4) * N_HEADS + n) * HDIM + lq;
#pragma unroll
  for (int ntl = 0; ntl < 16; ++ntl)
#pragma unroll
    for (int r = 0; r < 4; ++r)
      ebase[(size_t)r * (N_HEADS * HDIM) + ntl * 16] = f2bf(O[ntl][r] * inv[r]);
}

// ---------------------------------------------------------------------------
// GEMM 3: output projection. out[8192 x 2048] = E(bf16) @ out_w[2048 x 2048].
// ---------------------------------------------------------------------------
__global__ __launch_bounds__(256) void gemm_out(const u16* __restrict__ E,
                                                const float* __restrict__ ow,
                                                float* __restrict__ out) {
  __shared__ float As[16][68];
  __shared__ float Bs[16][68];
  const int t = threadIdx.x;
  const int nt = blockIdx.x;
  const int mt = blockIdx.y;
  const int row0 = mt * 64, col0 = nt * 64;
  const int tm = t & 15, tn = t >> 4;
  const int lm = t >> 2, lkq = t & 3;
  float acc[4][4] = {};
  for (int k0 = 0; k0 < D_MODEL; k0 += 16) {
    const uint2 a2 =
        *(const uint2*)(E + (size_t)(row0 + lm) * D_MODEL + k0 + lkq * 4);
    As[lkq * 4 + 0][lm] = __uint_as_float(a2.x << 16);
    As[lkq * 4 + 1][lm] = __uint_as_float(a2.x & 0xffff0000u);
    As[lkq * 4 + 2][lm] = __uint_as_float(a2.y << 16);
    As[lkq * 4 + 3][lm] = __uint_as_float(a2.y & 0xffff0000u);
    float4 b4 =
        *(const float4*)(ow + (size_t)(k0 + tn) * D_MODEL + col0 + tm * 4);
    *(float4*)&Bs[tn][tm * 4] = b4;
    __syncthreads();
#pragma unroll
    for (int k = 0; k < 16; ++k) {
      float4 a = *(const float4*)&As[k][tm * 4];
      float4 b = *(const float4*)&Bs[k][tn * 4];
      float av[4] = {a.x, a.y, a.z, a.w};
      float bv[4] = {b.x, b.y, b.z, b.w};
#pragma unroll
      for (int i = 0; i < 4; ++i)
#pragma unroll
        for (int j = 0; j < 4; ++j) acc[i][j] = fmaf(av[i], bv[j], acc[i][j]);
    }
    __syncthreads();
  }
#pragma unroll
  for (int i = 0; i < 4; ++i) {
    const int rrow = row0 + tm * 4 + i;
    const int ccol = col0 + tn * 4;
    *(float4*)(out + (size_t)rrow * D_MODEL + ccol) =
        make_float4(acc[i][0], acc[i][1], acc[i][2], acc[i][3]);
  }
}

// ---------------------------------------------------------------------------
extern "C" void kernel_launch(void* const* d_in, const int* in_sizes, int n_in,
                              void* d_out, int out_size, void* d_ws,
                              size_t ws_size, hipStream_t stream) {
  const float* x = (const float*)d_in[0];
  const int* segpos = (const int*)d_in[1];
  // d_in[2] = attn_mask (causal tril) — analytic, not read.
  const float* qw = (const float*)d_in[3];
  const float* kvw = (const float*)d_in[4];
  const float* ow = (const float*)d_in[5];
  float* out = (float*)d_out;

  char* ws = (char*)d_ws;
  u16* Qb = (u16*)ws;                                   // 32 MiB
  u16* Kb = (u16*)(ws + (size_t)33554432);              // 4 MiB
  u16* Vt = (u16*)(ws + (size_t)33554432 + 4194304);    // 4 MiB (transposed)
  u16* Eb = (u16*)(ws + (size_t)33554432 + 8388608);    // 32 MiB

  hipLaunchKernelGGL(gemm_qkv, dim3(4, 128, 10), dim3(256), 0, stream, x, qw,
                     kvw, Qb, Kb, Vt);
  hipLaunchKernelGGL(rope_kernel, dim3(8192), dim3(256), 0, stream, Qb, Kb,
                     segpos);
  hipLaunchKernelGGL(attn_mfma, dim3(64, N_HEADS, 2), dim3(256), 0, stream, Qb,
                     Kb, Vt, Eb);
  hipLaunchKernelGGL(gemm_out, dim3(32, 128), dim3(256), 0, stream, Eb, ow,
                     out);
}

// Round 3
// 1103.197 us; speedup vs baseline: 6.8030x; 2.4614x over previous
//
#include <hip/hip_runtime.h>

// Problem constants: B=2, T=4096, D=2048, N=8 heads, K=1 kv-head, H=256
#define T_SEQ 4096
#define D_MODEL 2048
#define N_HEADS 8
#define HDIM 256

typedef unsigned int uint32;
typedef unsigned short u16;
typedef __attribute__((ext_vector_type(8))) short short8;  // 8 bf16 (4 VGPRs)
typedef __attribute__((ext_vector_type(4))) float f32x4;

__device__ __forceinline__ float bf2f(u16 v) {
  return __uint_as_float(((uint32)v) << 16);
}
__device__ __forceinline__ u16 f2bf(float f) {
  uint32 u = __float_as_uint(f);
  u += 0x7fffu + ((u >> 16) & 1u);  // round-to-nearest-even
  return (u16)(u >> 16);
}
__device__ __forceinline__ uint2 pack4(const f32x4 v) {
  uint2 r;
  r.x = (uint32)f2bf(v[0]) | ((uint32)f2bf(v[1]) << 16);
  r.y = (uint32)f2bf(v[2]) | ((uint32)f2bf(v[3]) << 16);
  return r;
}
// async global->LDS, 16B per lane; LDS dest must be lane-contiguous.
__device__ __forceinline__ void gload16(const u16* g, u16* l) {
  __builtin_amdgcn_global_load_lds(
      (const __attribute__((address_space(1))) unsigned int*)g,
      (__attribute__((address_space(3))) unsigned int*)l, 16, 0, 0);
}

// ---------------------------------------------------------------------------
// Prep 1: x (f32) -> xb (bf16), row-major [8192][2048].
// ---------------------------------------------------------------------------
__global__ __launch_bounds__(256) void convert_x(const float* __restrict__ x,
                                                 u16* __restrict__ xb) {
  const int idx = blockIdx.x * 256 + threadIdx.x;  // 4 elems each
  float4 v = *(const float4*)(x + (size_t)idx * 4);
  uint2 pk;
  pk.x = (uint32)f2bf(v.x) | ((uint32)f2bf(v.y) << 16);
  pk.y = (uint32)f2bf(v.z) | ((uint32)f2bf(v.w) << 16);
  *(uint2*)(xb + (size_t)idx * 4) = pk;
}

// ---------------------------------------------------------------------------
// Prep 2: transpose+convert weights to bf16 B^T layouts:
//   z=0: W_all[d][c] (c<2048: qw head c>>8 col c&255; else kv) -> Wt[c][d]
//   z=1: ow[k][d] (k = n*256+h)                                -> Owt[d][k]
// 64x64 tiles through LDS.
// ---------------------------------------------------------------------------
__global__ __launch_bounds__(256) void prep_weights(
    const float* __restrict__ qw, const float* __restrict__ kvw,
    const float* __restrict__ ow, u16* __restrict__ Wt, u16* __restrict__ Owt) {
  __shared__ float Ts[64][65];
  const int t = threadIdx.x;
  const int tx = blockIdx.x, ty = blockIdx.y, z = blockIdx.z;
  const float* src;
  int srcStride;
  u16* dst;
  if (z == 0) {
    const int c0 = tx * 64;
    const float* base = (c0 < 2048)
                            ? qw + (size_t)(c0 >> 8) * D_MODEL * HDIM
                            : kvw + (size_t)((c0 - 2048) >> 8) * D_MODEL * HDIM;
    src = base + (c0 & 255);
    srcStride = HDIM;
    dst = Wt + (size_t)c0 * D_MODEL;
  } else {
    if (tx >= 32) return;
    src = ow + tx * 64;
    srcStride = D_MODEL;
    dst = Owt + (size_t)tx * 64 * D_MODEL;
  }
  const int d0 = ty * 64;
  const int r = t >> 4, c4 = (t & 15) * 4;
#pragma unroll
  for (int i = 0; i < 4; ++i) {
    float4 v = *(const float4*)(src + (size_t)(d0 + r + i * 16) * srcStride + c4);
    *(float4*)&Ts[r + i * 16][c4] = v;
  }
  __syncthreads();
#pragma unroll
  for (int i = 0; i < 4; ++i) {
    const int crow = r + i * 16;  // output row (source col)
    uint2 pk;
    pk.x = (uint32)f2bf(Ts[c4 + 0][crow]) | ((uint32)f2bf(Ts[c4 + 1][crow]) << 16);
    pk.y = (uint32)f2bf(Ts[c4 + 2][crow]) | ((uint32)f2bf(Ts[c4 + 3][crow]) << 16);
    *(uint2*)(dst + (size_t)crow * D_MODEL + d0 + c4) = pk;
  }
}

// ---------------------------------------------------------------------------
// MFMA GEMM 1: [xb 8192x2048 bf16] @ [Wt^T] -> Q/K/V.  cols: 0..2047 Q
// (row-major [row][n*256+h]), 2048..2303 K, 2304..2559 V (written transposed
// Vt[b][h][s] -- natural from C layout: lane holds 4 consecutive rows).
// 128x128 tile, BK=32, 4 waves, 4x4 16x16x32 MFMA tiles per wave.
// ---------------------------------------------------------------------------
__global__ __launch_bounds__(256) void gemm_qkv_mfma(
    const u16* __restrict__ xb, const u16* __restrict__ Wt,
    u16* __restrict__ Qb, u16* __restrict__ Kb, u16* __restrict__ Vt) {
  __shared__ u16 Asm[128][32];
  __shared__ u16 Bsm[128][32];
  const int t = threadIdx.x;
  const int w = t >> 6, l = t & 63, quad = l >> 4, lq = l & 15;
  const int wm = w & 1, wn = w >> 1;
  const int col0 = blockIdx.x * 128, row0 = blockIdx.y * 128;
  const u16* ga0 = xb + (size_t)(row0 + (t >> 2)) * D_MODEL + (t & 3) * 8;
  const u16* ga1 = ga0 + (size_t)64 * D_MODEL;
  const u16* gb0 = Wt + (size_t)(col0 + (t >> 2)) * D_MODEL + (t & 3) * 8;
  const u16* gb1 = gb0 + (size_t)64 * D_MODEL;
  u16* lA0 = &Asm[0][0] + t * 8;
  u16* lA1 = lA0 + 2048;
  u16* lB0 = &Bsm[0][0] + t * 8;
  u16* lB1 = lB0 + 2048;
  f32x4 acc[4][4];
#pragma unroll
  for (int i = 0; i < 4; ++i)
#pragma unroll
    for (int j = 0; j < 4; ++j) acc[i][j] = (f32x4){0.f, 0.f, 0.f, 0.f};
  for (int k0 = 0; k0 < D_MODEL; k0 += 32) {
    gload16(ga0 + k0, lA0);
    gload16(ga1 + k0, lA1);
    gload16(gb0 + k0, lB0);
    gload16(gb1 + k0, lB1);
    __syncthreads();
    short8 af[4], bf[4];
#pragma unroll
    for (int i = 0; i < 4; ++i)
      af[i] = *(const short8*)&Asm[wm * 64 + i * 16 + lq][quad * 8];
#pragma unroll
    for (int j = 0; j < 4; ++j)
      bf[j] = *(const short8*)&Bsm[wn * 64 + j * 16 + lq][quad * 8];
#pragma unroll
    for (int i = 0; i < 4; ++i)
#pragma unroll
      for (int j = 0; j < 4; ++j)
        acc[i][j] =
            __builtin_amdgcn_mfma_f32_16x16x32_bf16(af[i], bf[j], acc[i][j], 0, 0, 0);
    __syncthreads();
  }
  const int b = row0 >> 12, sbase = row0 & 4095;
#pragma unroll
  for (int i = 0; i < 4; ++i) {
    const int rowloc = wm * 64 + i * 16 + quad * 4;
#pragma unroll
    for (int j = 0; j < 4; ++j) {
      const int col = col0 + wn * 64 + j * 16 + lq;
      if (col < 2048) {
#pragma unroll
        for (int r = 0; r < 4; ++r)
          Qb[(size_t)(row0 + rowloc + r) * 2048 + col] = f2bf(acc[i][j][r]);
      } else if (col < 2304) {
#pragma unroll
        for (int r = 0; r < 4; ++r)
          Kb[(size_t)(row0 + rowloc + r) * HDIM + (col - 2048)] =
              f2bf(acc[i][j][r]);
      } else {
        *(uint2*)(Vt + ((size_t)b * HDIM + col - 2304) * T_SEQ + sbase + rowloc) =
            pack4(acc[i][j]);
      }
    }
  }
}

// ---------------------------------------------------------------------------
// RoPE (in-place on bf16 Q and K) + query scaling by H^-0.5.
// ---------------------------------------------------------------------------
__global__ __launch_bounds__(256) void rope_kernel(u16* __restrict__ Qb,
                                                   u16* __restrict__ Kb,
                                                   const int* __restrict__ segpos) {
  const int bt = blockIdx.x;
  const int tid = threadIdx.x;
  const float fpos = (float)segpos[bt];
  const float k_ln = 9.210340371976184f / 128.0f;  // ln(10000)/(H/2)
  for (int p = tid; p < 1024; p += 256) {
    const int n = p >> 7, i = p & 127;
    const size_t base = (size_t)bt * (N_HEADS * HDIM) + (size_t)n * HDIM;
    const float th = fpos * expf(-(float)i * k_ln);
    float s, c;
    sincosf(th, &s, &c);
    const float f1 = bf2f(Qb[base + i]);
    const float f2 = bf2f(Qb[base + i + 128]);
    Qb[base + i] = f2bf((f1 * c - f2 * s) * 0.0625f);
    Qb[base + i + 128] = f2bf((f2 * c + f1 * s) * 0.0625f);
  }
  if (tid < 128) {
    const int i = tid;
    const size_t base = (size_t)bt * HDIM;
    const float th = fpos * expf(-(float)i * k_ln);
    float s, c;
    sincosf(th, &s, &c);
    const float f1 = bf2f(Kb[base + i]);
    const float f2 = bf2f(Kb[base + i + 128]);
    Kb[base + i] = f2bf(f1 * c - f2 * s);
    Kb[base + i + 128] = f2bf(f2 * c + f1 * s);
  }
}

// ---------------------------------------------------------------------------
// MFMA flash attention (causal, MQA) -- unchanged from round 2.
// ---------------------------------------------------------------------------
__global__ __launch_bounds__(256) void attn_mfma(const u16* __restrict__ Qb,
                                                 const u16* __restrict__ Kb,
                                                 const u16* __restrict__ Vt,
                                                 u16* __restrict__ Eb) {
  __shared__ u16 Ks[32][264];
  __shared__ u16 Vs[256][40];
  __shared__ u16 Ps[4][16][40];
  const int t = threadIdx.x;
  const int w = t >> 6, l = t & 63;
  const int quad = l >> 4, lq = l & 15;
  const int qt = (int)gridDim.x - 1 - (int)blockIdx.x;  // heavy tiles first
  const int n = blockIdx.y, b = blockIdx.z;
  const int q0 = qt * 64;
  const int wrow0 = q0 + w * 16;
  short8 qf[8];
  {
    const u16* qbase =
        Qb + (((size_t)b * T_SEQ + wrow0 + lq) * N_HEADS + n) * HDIM + quad * 8;
#pragma unroll
    for (int c = 0; c < 8; ++c) qf[c] = *(const short8*)(qbase + c * 32);
  }
  f32x4 O[16];
#pragma unroll
  for (int i = 0; i < 16; ++i) O[i] = (f32x4){0.f, 0.f, 0.f, 0.f};
  float m_i[4] = {-1e30f, -1e30f, -1e30f, -1e30f};
  float l_i[4] = {0.f, 0.f, 0.f, 0.f};
  const u16* kgbase = Kb + (size_t)b * T_SEQ * HDIM;
  const u16* vgbase = Vt + (size_t)b * HDIM * T_SEQ;
  const int nst = 2 * qt + 2;
  for (int st = 0; st < nst; ++st) {
    const int s0 = st * 32;
    __syncthreads();
#pragma unroll
    for (int p = 0; p < 4; ++p) {
      const int chunk = p * 256 + t;
      const int row = chunk >> 5, col = chunk & 31;
      *(uint4*)&Ks[row][col * 8] =
          *(const uint4*)(kgbase + (size_t)(s0 + row) * HDIM + col * 8);
    }
#pragma unroll
    for (int p = 0; p < 4; ++p) {
      const int chunk = p * 256 + t;
      const int row = chunk >> 2, c4 = chunk & 3;
      *(uint4*)&Vs[row][c4 * 8] =
          *(const uint4*)(vgbase + (size_t)row * T_SEQ + s0 + c4 * 8);
    }
    __syncthreads();
    if (s0 <= wrow0 + 15) {
      f32x4 sa0 = (f32x4){0.f, 0.f, 0.f, 0.f};
      f32x4 sa1 = (f32x4){0.f, 0.f, 0.f, 0.f};
#pragma unroll
      for (int c = 0; c < 8; ++c) {
        short8 k0 = *(const short8*)&Ks[lq][c * 32 + quad * 8];
        short8 k1 = *(const short8*)&Ks[16 + lq][c * 32 + quad * 8];
        sa0 = __builtin_amdgcn_mfma_f32_16x16x32_bf16(qf[c], k0, sa0, 0, 0, 0);
        sa1 = __builtin_amdgcn_mfma_f32_16x16x32_bf16(qf[c], k1, sa1, 0, 0, 0);
      }
      if (s0 + 31 > wrow0) {
#pragma unroll
        for (int r = 0; r < 4; ++r) {
          const int rw = wrow0 + quad * 4 + r;
          if (s0 + lq > rw) sa0[r] = -1e30f;
          if (s0 + 16 + lq > rw) sa1[r] = -1e30f;
        }
      }
      float al[4];
#pragma unroll
      for (int r = 0; r < 4; ++r) {
        float mx = fmaxf(sa0[r], sa1[r]);
        mx = fmaxf(mx, __shfl_xor(mx, 1));
        mx = fmaxf(mx, __shfl_xor(mx, 2));
        mx = fmaxf(mx, __shfl_xor(mx, 4));
        mx = fmaxf(mx, __shfl_xor(mx, 8));
        const float mnew = fmaxf(m_i[r], mx);
        const float a = __expf(m_i[r] - mnew);
        const float p0 = __expf(sa0[r] - mnew);
        const float p1 = __expf(sa1[r] - mnew);
        float rs = p0 + p1;
        rs += __shfl_xor(rs, 1);
        rs += __shfl_xor(rs, 2);
        rs += __shfl_xor(rs, 4);
        rs += __shfl_xor(rs, 8);
        l_i[r] = l_i[r] * a + rs;
        m_i[r] = mnew;
        al[r] = a;
        Ps[w][quad * 4 + r][lq] = f2bf(p0);
        Ps[w][quad * 4 + r][16 + lq] = f2bf(p1);
      }
#pragma unroll
      for (int ntl = 0; ntl < 16; ++ntl) {
        O[ntl][0] *= al[0];
        O[ntl][1] *= al[1];
        O[ntl][2] *= al[2];
        O[ntl][3] *= al[3];
      }
      __asm__ volatile("s_waitcnt lgkmcnt(0)" ::: "memory");
      short8 pf = *(const short8*)&Ps[w][lq][quad * 8];
#pragma unroll
      for (int ntl = 0; ntl < 16; ++ntl) {
        short8 vf = *(const short8*)&Vs[ntl * 16 + lq][quad * 8];
        O[ntl] = __builtin_amdgcn_mfma_f32_16x16x32_bf16(pf, vf, O[ntl], 0, 0, 0);
      }
    }
  }
  float inv[4];
#pragma unroll
  for (int r = 0; r < 4; ++r) inv[r] = 1.0f / l_i[r];
  u16* ebase =
      Eb + (((size_t)b * T_SEQ + wrow0 + quad * 4) * N_HEADS + n) * HDIM + lq;
#pragma unroll
  for (int ntl = 0; ntl < 16; ++ntl)
#pragma unroll
    for (int r = 0; r < 4; ++r)
      ebase[(size_t)r * (N_HEADS * HDIM) + ntl * 16] = f2bf(O[ntl][r] * inv[r]);
}

// ---------------------------------------------------------------------------
// MFMA GEMM 2: out[8192x2048 f32] = Eb(bf16) @ Owt^T.
// ---------------------------------------------------------------------------
__global__ __launch_bounds__(256) void gemm_out_mfma(const u16* __restrict__ E,
                                                     const u16* __restrict__ Owt,
                                                     float* __restrict__ out) {
  __shared__ u16 Asm[128][32];
  __shared__ u16 Bsm[128][32];
  const int t = threadIdx.x;
  const int w = t >> 6, l = t & 63, quad = l >> 4, lq = l & 15;
  const int wm = w & 1, wn = w >> 1;
  const int col0 = blockIdx.x * 128, row0 = blockIdx.y * 128;
  const u16* ga0 = E + (size_t)(row0 + (t >> 2)) * D_MODEL + (t & 3) * 8;
  const u16* ga1 = ga0 + (size_t)64 * D_MODEL;
  const u16* gb0 = Owt + (size_t)(col0 + (t >> 2)) * D_MODEL + (t & 3) * 8;
  const u16* gb1 = gb0 + (size_t)64 * D_MODEL;
  u16* lA0 = &Asm[0][0] + t * 8;
  u16* lA1 = lA0 + 2048;
  u16* lB0 = &Bsm[0][0] + t * 8;
  u16* lB1 = lB0 + 2048;
  f32x4 acc[4][4];
#pragma unroll
  for (int i = 0; i < 4; ++i)
#pragma unroll
    for (int j = 0; j < 4; ++j) acc[i][j] = (f32x4){0.f, 0.f, 0.f, 0.f};
  for (int k0 = 0; k0 < D_MODEL; k0 += 32) {
    gload16(ga0 + k0, lA0);
    gload16(ga1 + k0, lA1);
    gload16(gb0 + k0, lB0);
    gload16(gb1 + k0, lB1);
    __syncthreads();
    short8 af[4], bf[4];
#pragma unroll
    for (int i = 0; i < 4; ++i)
      af[i] = *(const short8*)&Asm[wm * 64 + i * 16 + lq][quad * 8];
#pragma unroll
    for (int j = 0; j < 4; ++j)
      bf[j] = *(const short8*)&Bsm[wn * 64 + j * 16 + lq][quad * 8];
#pragma unroll
    for (int i = 0; i < 4; ++i)
#pragma unroll
      for (int j = 0; j < 4; ++j)
        acc[i][j] =
            __builtin_amdgcn_mfma_f32_16x16x32_bf16(af[i], bf[j], acc[i][j], 0, 0, 0);
    __syncthreads();
  }
#pragma unroll
  for (int i = 0; i < 4; ++i) {
    const int row = row0 + wm * 64 + i * 16 + quad * 4;
#pragma unroll
    for (int j = 0; j < 4; ++j) {
      const int col = col0 + wn * 64 + j * 16 + lq;
#pragma unroll
      for (int r = 0; r < 4; ++r)
        out[(size_t)(row + r) * D_MODEL + col] = acc[i][j][r];
    }
  }
}

// ---------------------------------------------------------------------------
extern "C" void kernel_launch(void* const* d_in, const int* in_sizes, int n_in,
                              void* d_out, int out_size, void* d_ws,
                              size_t ws_size, hipStream_t stream) {
  const float* x = (const float*)d_in[0];
  const int* segpos = (const int*)d_in[1];
  // d_in[2] = attn_mask (causal tril) — analytic, not read.
  const float* qw = (const float*)d_in[3];
  const float* kvw = (const float*)d_in[4];
  const float* ow = (const float*)d_in[5];
  float* out = (float*)d_out;

  char* ws = (char*)d_ws;
  u16* Qb = (u16*)ws;                                    // 32 MiB
  u16* Kb = (u16*)(ws + (size_t)33554432);               // 4 MiB
  u16* Vt = (u16*)(ws + (size_t)37748736);               // 4 MiB (transposed)
  u16* xb = (u16*)(ws + (size_t)41943040);               // 32 MiB (aliases Eb)
  u16* Eb = xb;  // xb dead after gemm_qkv_mfma
  u16* Wt = (u16*)(ws + (size_t)75497472);               // 10 MiB
  u16* Owt = (u16*)(ws + (size_t)85983232);              // 8 MiB  (total 90 MiB)

  hipLaunchKernelGGL(convert_x, dim3(16384), dim3(256), 0, stream, x, xb);
  hipLaunchKernelGGL(prep_weights, dim3(40, 32, 2), dim3(256), 0, stream, qw,
                     kvw, ow, Wt, Owt);
  hipLaunchKernelGGL(gemm_qkv_mfma, dim3(20, 64), dim3(256), 0, stream, xb, Wt,
                     Qb, Kb, Vt);
  hipLaunchKernelGGL(rope_kernel, dim3(8192), dim3(256), 0, stream, Qb, Kb,
                     segpos);
  hipLaunchKernelGGL(attn_mfma, dim3(64, N_HEADS, 2), dim3(256), 0, stream, Qb,
                     Kb, Vt, Eb);
  hipLaunchKernelGGL(gemm_out_mfma, dim3(16, 64), dim3(256), 0, stream, Eb, Owt,
                     out);
}

// Round 4
// 814.794 us; speedup vs baseline: 9.2110x; 1.3540x over previous
//
#include <hip/hip_runtime.h>

// Problem constants: B=2, T=4096, D=2048, N=8 heads, K=1 kv-head, H=256
#define T_SEQ 4096
#define D_MODEL 2048
#define N_HEADS 8
#define HDIM 256

typedef unsigned int uint32;
typedef unsigned short u16;
typedef __attribute__((ext_vector_type(8))) short short8;  // 8 bf16 (4 VGPRs)
typedef __attribute__((ext_vector_type(4))) float f32x4;

__device__ __forceinline__ float bf2f(u16 v) {
  return __uint_as_float(((uint32)v) << 16);
}
__device__ __forceinline__ u16 f2bf(float f) {
  uint32 u = __float_as_uint(f);
  u += 0x7fffu + ((u >> 16) & 1u);  // round-to-nearest-even
  return (u16)(u >> 16);
}
__device__ __forceinline__ uint2 pack4(const f32x4 v) {
  uint2 r;
  r.x = (uint32)f2bf(v[0]) | ((uint32)f2bf(v[1]) << 16);
  r.y = (uint32)f2bf(v[2]) | ((uint32)f2bf(v[3]) << 16);
  return r;
}
// async global->LDS, 16B per lane; LDS dest must be lane-contiguous.
__device__ __forceinline__ void gload16(const u16* g, u16* l) {
  __builtin_amdgcn_global_load_lds(
      (const __attribute__((address_space(1))) unsigned int*)g,
      (__attribute__((address_space(3))) unsigned int*)l, 16, 0, 0);
}

// ---------------------------------------------------------------------------
// Prep 1: x (f32) -> xb (bf16), row-major [8192][2048].
// ---------------------------------------------------------------------------
__global__ __launch_bounds__(256) void convert_x(const float* __restrict__ x,
                                                 u16* __restrict__ xb) {
  const int idx = blockIdx.x * 256 + threadIdx.x;  // 4 elems each
  float4 v = *(const float4*)(x + (size_t)idx * 4);
  uint2 pk;
  pk.x = (uint32)f2bf(v.x) | ((uint32)f2bf(v.y) << 16);
  pk.y = (uint32)f2bf(v.z) | ((uint32)f2bf(v.w) << 16);
  *(uint2*)(xb + (size_t)idx * 4) = pk;
}

// ---------------------------------------------------------------------------
// Prep 2: transpose+convert weights to bf16 B^T layouts:
//   z=0: W_all[d][c] (c<2048: qw head c>>8 col c&255; else kv) -> Wt[c][d]
//   z=1: ow[k][d] (k = n*256+h)                                -> Owt[d][k]
// ---------------------------------------------------------------------------
__global__ __launch_bounds__(256) void prep_weights(
    const float* __restrict__ qw, const float* __restrict__ kvw,
    const float* __restrict__ ow, u16* __restrict__ Wt, u16* __restrict__ Owt) {
  __shared__ float Ts[64][65];
  const int t = threadIdx.x;
  const int tx = blockIdx.x, ty = blockIdx.y, z = blockIdx.z;
  const float* src;
  int srcStride;
  u16* dst;
  if (z == 0) {
    const int c0 = tx * 64;
    const float* base = (c0 < 2048)
                            ? qw + (size_t)(c0 >> 8) * D_MODEL * HDIM
                            : kvw + (size_t)((c0 - 2048) >> 8) * D_MODEL * HDIM;
    src = base + (c0 & 255);
    srcStride = HDIM;
    dst = Wt + (size_t)c0 * D_MODEL;
  } else {
    if (tx >= 32) return;
    src = ow + tx * 64;
    srcStride = D_MODEL;
    dst = Owt + (size_t)tx * 64 * D_MODEL;
  }
  const int d0 = ty * 64;
  const int r = t >> 4, c4 = (t & 15) * 4;
#pragma unroll
  for (int i = 0; i < 4; ++i) {
    float4 v = *(const float4*)(src + (size_t)(d0 + r + i * 16) * srcStride + c4);
    *(float4*)&Ts[r + i * 16][c4] = v;
  }
  __syncthreads();
#pragma unroll
  for (int i = 0; i < 4; ++i) {
    const int crow = r + i * 16;  // output row (source col)
    uint2 pk;
    pk.x = (uint32)f2bf(Ts[c4 + 0][crow]) | ((uint32)f2bf(Ts[c4 + 1][crow]) << 16);
    pk.y = (uint32)f2bf(Ts[c4 + 2][crow]) | ((uint32)f2bf(Ts[c4 + 3][crow]) << 16);
    *(uint2*)(dst + (size_t)crow * D_MODEL + d0 + c4) = pk;
  }
}

// ---------------------------------------------------------------------------
// MFMA GEMM 1: [xb 8192x2048 bf16] @ [Wt^T] -> Q/K/V.  cols: 0..2047 Q,
// 2048..2303 K, 2304..2559 V (written transposed Vt[b][h][s]).
// ---------------------------------------------------------------------------
__global__ __launch_bounds__(256) void gemm_qkv_mfma(
    const u16* __restrict__ xb, const u16* __restrict__ Wt,
    u16* __restrict__ Qb, u16* __restrict__ Kb, u16* __restrict__ Vt) {
  __shared__ u16 Asm[128][32];
  __shared__ u16 Bsm[128][32];
  const int t = threadIdx.x;
  const int w = t >> 6, l = t & 63, quad = l >> 4, lq = l & 15;
  const int wm = w & 1, wn = w >> 1;
  const int col0 = blockIdx.x * 128, row0 = blockIdx.y * 128;
  const u16* ga0 = xb + (size_t)(row0 + (t >> 2)) * D_MODEL + (t & 3) * 8;
  const u16* ga1 = ga0 + (size_t)64 * D_MODEL;
  const u16* gb0 = Wt + (size_t)(col0 + (t >> 2)) * D_MODEL + (t & 3) * 8;
  const u16* gb1 = gb0 + (size_t)64 * D_MODEL;
  u16* lA0 = &Asm[0][0] + t * 8;
  u16* lA1 = lA0 + 2048;
  u16* lB0 = &Bsm[0][0] + t * 8;
  u16* lB1 = lB0 + 2048;
  f32x4 acc[4][4];
#pragma unroll
  for (int i = 0; i < 4; ++i)
#pragma unroll
    for (int j = 0; j < 4; ++j) acc[i][j] = (f32x4){0.f, 0.f, 0.f, 0.f};
  for (int k0 = 0; k0 < D_MODEL; k0 += 32) {
    gload16(ga0 + k0, lA0);
    gload16(ga1 + k0, lA1);
    gload16(gb0 + k0, lB0);
    gload16(gb1 + k0, lB1);
    __syncthreads();
    short8 af[4], bf[4];
#pragma unroll
    for (int i = 0; i < 4; ++i)
      af[i] = *(const short8*)&Asm[wm * 64 + i * 16 + lq][quad * 8];
#pragma unroll
    for (int j = 0; j < 4; ++j)
      bf[j] = *(const short8*)&Bsm[wn * 64 + j * 16 + lq][quad * 8];
#pragma unroll
    for (int i = 0; i < 4; ++i)
#pragma unroll
      for (int j = 0; j < 4; ++j)
        acc[i][j] =
            __builtin_amdgcn_mfma_f32_16x16x32_bf16(af[i], bf[j], acc[i][j], 0, 0, 0);
    __syncthreads();
  }
  const int b = row0 >> 12, sbase = row0 & 4095;
#pragma unroll
  for (int i = 0; i < 4; ++i) {
    const int rowloc = wm * 64 + i * 16 + quad * 4;
#pragma unroll
    for (int j = 0; j < 4; ++j) {
      const int col = col0 + wn * 64 + j * 16 + lq;
      if (col < 2048) {
#pragma unroll
        for (int r = 0; r < 4; ++r)
          Qb[(size_t)(row0 + rowloc + r) * 2048 + col] = f2bf(acc[i][j][r]);
      } else if (col < 2304) {
#pragma unroll
        for (int r = 0; r < 4; ++r)
          Kb[(size_t)(row0 + rowloc + r) * HDIM + (col - 2048)] =
              f2bf(acc[i][j][r]);
      } else {
        *(uint2*)(Vt + ((size_t)b * HDIM + col - 2304) * T_SEQ + sbase + rowloc) =
            pack4(acc[i][j]);
      }
    }
  }
}

// ---------------------------------------------------------------------------
// RoPE (in-place on bf16 Q and K) + query scaling by H^-0.5.
// ---------------------------------------------------------------------------
__global__ __launch_bounds__(256) void rope_kernel(u16* __restrict__ Qb,
                                                   u16* __restrict__ Kb,
                                                   const int* __restrict__ segpos) {
  const int bt = blockIdx.x;
  const int tid = threadIdx.x;
  const float fpos = (float)segpos[bt];
  const float k_ln = 9.210340371976184f / 128.0f;  // ln(10000)/(H/2)
  for (int p = tid; p < 1024; p += 256) {
    const int n = p >> 7, i = p & 127;
    const size_t base = (size_t)bt * (N_HEADS * HDIM) + (size_t)n * HDIM;
    const float th = fpos * expf(-(float)i * k_ln);
    float s, c;
    sincosf(th, &s, &c);
    const float f1 = bf2f(Qb[base + i]);
    const float f2 = bf2f(Qb[base + i + 128]);
    Qb[base + i] = f2bf((f1 * c - f2 * s) * 0.0625f);
    Qb[base + i + 128] = f2bf((f2 * c + f1 * s) * 0.0625f);
  }
  if (tid < 128) {
    const int i = tid;
    const size_t base = (size_t)bt * HDIM;
    const float th = fpos * expf(-(float)i * k_ln);
    float s, c;
    sincosf(th, &s, &c);
    const float f1 = bf2f(Kb[base + i]);
    const float f2 = bf2f(Kb[base + i + 128]);
    Kb[base + i] = f2bf(f1 * c - f2 * s);
    Kb[base + i + 128] = f2bf(f2 * c + f1 * s);
  }
}

// ---------------------------------------------------------------------------
// MFMA flash attention (causal, MQA).
// Round 4: complementary-pair load balancing. Block bid processes Q-tiles
// {63-bid, bid} sequentially -> every block does exactly 130 K-iters.
// Grid 32 x 8 x 2 = 512 equal blocks (~2/CU steady, LDS caps at 3).
// ---------------------------------------------------------------------------
__global__ __launch_bounds__(256) void attn_mfma(const u16* __restrict__ Qb,
                                                 const u16* __restrict__ Kb,
                                                 const u16* __restrict__ Vt,
                                                 u16* __restrict__ Eb) {
  __shared__ u16 Ks[32][264];
  __shared__ u16 Vs[256][40];
  __shared__ u16 Ps[4][16][40];
  const int t = threadIdx.x;
  const int w = t >> 6, l = t & 63;
  const int quad = l >> 4, lq = l & 15;
  const int bid = blockIdx.x;  // 0..31
  const int n = blockIdx.y, b = blockIdx.z;
  const u16* kgbase = Kb + (size_t)b * T_SEQ * HDIM;
  const u16* vgbase = Vt + (size_t)b * HDIM * T_SEQ;

#pragma unroll 1
  for (int ti = 0; ti < 2; ++ti) {
    const int qt = ti ? bid : 63 - bid;  // heavy tile first
    const int q0 = qt * 64;
    const int wrow0 = q0 + w * 16;

    // Q fragments: 8 chunks of K=32 head-dims, in registers for this tile.
    short8 qf[8];
    {
      const u16* qbase = Qb +
          (((size_t)b * T_SEQ + wrow0 + lq) * N_HEADS + n) * HDIM + quad * 8;
#pragma unroll
      for (int c = 0; c < 8; ++c) qf[c] = *(const short8*)(qbase + c * 32);
    }
    f32x4 O[16];
#pragma unroll
    for (int i = 0; i < 16; ++i) O[i] = (f32x4){0.f, 0.f, 0.f, 0.f};
    float m_i[4] = {-1e30f, -1e30f, -1e30f, -1e30f};
    float l_i[4] = {0.f, 0.f, 0.f, 0.f};

    const int nst = 2 * qt + 2;
    for (int st = 0; st < nst; ++st) {
      const int s0 = st * 32;
      __syncthreads();  // previous iteration's (or tile's) LDS reads done
#pragma unroll
      for (int p = 0; p < 4; ++p) {
        const int chunk = p * 256 + t;
        const int row = chunk >> 5, col = chunk & 31;
        *(uint4*)&Ks[row][col * 8] =
            *(const uint4*)(kgbase + (size_t)(s0 + row) * HDIM + col * 8);
      }
#pragma unroll
      for (int p = 0; p < 4; ++p) {
        const int chunk = p * 256 + t;
        const int row = chunk >> 2, c4 = chunk & 3;
        *(uint4*)&Vs[row][c4 * 8] =
            *(const uint4*)(vgbase + (size_t)row * T_SEQ + s0 + c4 * 8);
      }
      __syncthreads();
      if (s0 <= wrow0 + 15) {  // wave-uniform skip of fully-masked tiles
        f32x4 sa0 = (f32x4){0.f, 0.f, 0.f, 0.f};
        f32x4 sa1 = (f32x4){0.f, 0.f, 0.f, 0.f};
#pragma unroll
        for (int c = 0; c < 8; ++c) {
          short8 k0 = *(const short8*)&Ks[lq][c * 32 + quad * 8];
          short8 k1 = *(const short8*)&Ks[16 + lq][c * 32 + quad * 8];
          sa0 = __builtin_amdgcn_mfma_f32_16x16x32_bf16(qf[c], k0, sa0, 0, 0, 0);
          sa1 = __builtin_amdgcn_mfma_f32_16x16x32_bf16(qf[c], k1, sa1, 0, 0, 0);
        }
        if (s0 + 31 > wrow0) {  // diagonal tiles: causal mask
#pragma unroll
          for (int r = 0; r < 4; ++r) {
            const int rw = wrow0 + quad * 4 + r;
            if (s0 + lq > rw) sa0[r] = -1e30f;
            if (s0 + 16 + lq > rw) sa1[r] = -1e30f;
          }
        }
        float al[4];
#pragma unroll
        for (int r = 0; r < 4; ++r) {
          float mx = fmaxf(sa0[r], sa1[r]);
          mx = fmaxf(mx, __shfl_xor(mx, 1));
          mx = fmaxf(mx, __shfl_xor(mx, 2));
          mx = fmaxf(mx, __shfl_xor(mx, 4));
          mx = fmaxf(mx, __shfl_xor(mx, 8));
          const float mnew = fmaxf(m_i[r], mx);
          const float a = __expf(m_i[r] - mnew);
          const float p0 = __expf(sa0[r] - mnew);
          const float p1 = __expf(sa1[r] - mnew);
          float rs = p0 + p1;
          rs += __shfl_xor(rs, 1);
          rs += __shfl_xor(rs, 2);
          rs += __shfl_xor(rs, 4);
          rs += __shfl_xor(rs, 8);
          l_i[r] = l_i[r] * a + rs;
          m_i[r] = mnew;
          al[r] = a;
          Ps[w][quad * 4 + r][lq] = f2bf(p0);
          Ps[w][quad * 4 + r][16 + lq] = f2bf(p1);
        }
#pragma unroll
        for (int ntl = 0; ntl < 16; ++ntl) {
          O[ntl][0] *= al[0];
          O[ntl][1] *= al[1];
          O[ntl][2] *= al[2];
          O[ntl][3] *= al[3];
        }
        __asm__ volatile("s_waitcnt lgkmcnt(0)" ::: "memory");
        short8 pf = *(const short8*)&Ps[w][lq][quad * 8];
#pragma unroll
        for (int ntl = 0; ntl < 16; ++ntl) {
          short8 vf = *(const short8*)&Vs[ntl * 16 + lq][quad * 8];
          O[ntl] = __builtin_amdgcn_mfma_f32_16x16x32_bf16(pf, vf, O[ntl], 0, 0, 0);
        }
      }
    }
    // epilogue: normalize, store encoded bf16 for this tile
    float inv[4];
#pragma unroll
    for (int r = 0; r < 4; ++r) inv[r] = 1.0f / l_i[r];
    u16* ebase =
        Eb + (((size_t)b * T_SEQ + wrow0 + quad * 4) * N_HEADS + n) * HDIM + lq;
#pragma unroll
    for (int ntl = 0; ntl < 16; ++ntl)
#pragma unroll
      for (int r = 0; r < 4; ++r)
        ebase[(size_t)r * (N_HEADS * HDIM) + ntl * 16] = f2bf(O[ntl][r] * inv[r]);
  }
}

// ---------------------------------------------------------------------------
// MFMA GEMM 2: out[8192x2048 f32] = Eb(bf16) @ Owt^T.
// ---------------------------------------------------------------------------
__global__ __launch_bounds__(256) void gemm_out_mfma(const u16* __restrict__ E,
                                                     const u16* __restrict__ Owt,
                                                     float* __restrict__ out) {
  __shared__ u16 Asm[128][32];
  __shared__ u16 Bsm[128][32];
  const int t = threadIdx.x;
  const int w = t >> 6, l = t & 63, quad = l >> 4, lq = l & 15;
  const int wm = w & 1, wn = w >> 1;
  const int col0 = blockIdx.x * 128, row0 = blockIdx.y * 128;
  const u16* ga0 = E + (size_t)(row0 + (t >> 2)) * D_MODEL + (t & 3) * 8;
  const u16* ga1 = ga0 + (size_t)64 * D_MODEL;
  const u16* gb0 = Owt + (size_t)(col0 + (t >> 2)) * D_MODEL + (t & 3) * 8;
  const u16* gb1 = gb0 + (size_t)64 * D_MODEL;
  u16* lA0 = &Asm[0][0] + t * 8;
  u16* lA1 = lA0 + 2048;
  u16* lB0 = &Bsm[0][0] + t * 8;
  u16* lB1 = lB0 + 2048;
  f32x4 acc[4][4];
#pragma unroll
  for (int i = 0; i < 4; ++i)
#pragma unroll
    for (int j = 0; j < 4; ++j) acc[i][j] = (f32x4){0.f, 0.f, 0.f, 0.f};
  for (int k0 = 0; k0 < D_MODEL; k0 += 32) {
    gload16(ga0 + k0, lA0);
    gload16(ga1 + k0, lA1);
    gload16(gb0 + k0, lB0);
    gload16(gb1 + k0, lB1);
    __syncthreads();
    short8 af[4], bf[4];
#pragma unroll
    for (int i = 0; i < 4; ++i)
      af[i] = *(const short8*)&Asm[wm * 64 + i * 16 + lq][quad * 8];
#pragma unroll
    for (int j = 0; j < 4; ++j)
      bf[j] = *(const short8*)&Bsm[wn * 64 + j * 16 + lq][quad * 8];
#pragma unroll
    for (int i = 0; i < 4; ++i)
#pragma unroll
      for (int j = 0; j < 4; ++j)
        acc[i][j] =
            __builtin_amdgcn_mfma_f32_16x16x32_bf16(af[i], bf[j], acc[i][j], 0, 0, 0);
    __syncthreads();
  }
#pragma unroll
  for (int i = 0; i < 4; ++i) {
    const int row = row0 + wm * 64 + i * 16 + quad * 4;
#pragma unroll
    for (int j = 0; j < 4; ++j) {
      const int col = col0 + wn * 64 + j * 16 + lq;
#pragma unroll
      for (int r = 0; r < 4; ++r)
        out[(size_t)(row + r) * D_MODEL + col] = acc[i][j][r];
    }
  }
}

// ---------------------------------------------------------------------------
extern "C" void kernel_launch(void* const* d_in, const int* in_sizes, int n_in,
                              void* d_out, int out_size, void* d_ws,
                              size_t ws_size, hipStream_t stream) {
  const float* x = (const float*)d_in[0];
  const int* segpos = (const int*)d_in[1];
  // d_in[2] = attn_mask (causal tril) — analytic, not read.
  const float* qw = (const float*)d_in[3];
  const float* kvw = (const float*)d_in[4];
  const float* ow = (const float*)d_in[5];
  float* out = (float*)d_out;

  char* ws = (char*)d_ws;
  u16* Qb = (u16*)ws;                                    // 32 MiB
  u16* Kb = (u16*)(ws + (size_t)33554432);               // 4 MiB
  u16* Vt = (u16*)(ws + (size_t)37748736);               // 4 MiB (transposed)
  u16* xb = (u16*)(ws + (size_t)41943040);               // 32 MiB (aliases Eb)
  u16* Eb = xb;  // xb dead after gemm_qkv_mfma
  u16* Wt = (u16*)(ws + (size_t)75497472);               // 10 MiB
  u16* Owt = (u16*)(ws + (size_t)85983232);              // 8 MiB  (total 90 MiB)

  hipLaunchKernelGGL(convert_x, dim3(16384), dim3(256), 0, stream, x, xb);
  hipLaunchKernelGGL(prep_weights, dim3(40, 32, 2), dim3(256), 0, stream, qw,
                     kvw, ow, Wt, Owt);
  hipLaunchKernelGGL(gemm_qkv_mfma, dim3(20, 64), dim3(256), 0, stream, xb, Wt,
                     Qb, Kb, Vt);
  hipLaunchKernelGGL(rope_kernel, dim3(8192), dim3(256), 0, stream, Qb, Kb,
                     segpos);
  hipLaunchKernelGGL(attn_mfma, dim3(32, N_HEADS, 2), dim3(256), 0, stream, Qb,
                     Kb, Vt, Eb);
  hipLaunchKernelGGL(gemm_out_mfma, dim3(16, 64), dim3(256), 0, stream, Eb, Owt,
                     out);
}